// Round 2
// baseline (411.885 us; speedup 1.0000x reference)
//
#include <hip/hip_runtime.h>
#include <hip/hip_bf16.h>

// Problem dims
#define BB 64
#define TT 128
#define FIN 12
#define HH 128
#define GG 512  // 4*H

#define LOG2E 1.4426950408889634f
#define TWO_LOG2E 2.8853900817779268f

__device__ __forceinline__ float fexp2(float x) { return __builtin_amdgcn_exp2f(x); }
__device__ __forceinline__ float frcp(float x)  { return __builtin_amdgcn_rcpf(x); }

// tanh(x) = 1 - 2/(1+e^{2x}); correct limits at +/-inf via exp2->{inf,0}
__device__ __forceinline__ float tanh_f(float x) {
  return 1.0f - 2.0f * frcp(1.0f + fexp2(TWO_LOG2E * x));
}
__device__ __forceinline__ float sigm_f(float x) {
  return frcp(1.0f + fexp2(-LOG2E * x));
}

// quad_perm broadcast of quad-lane L: ctrl = L*0b01010101
template <int CTRL>
__device__ __forceinline__ float quad_bcast(float v) {
  return __int_as_float(
      __builtin_amdgcn_update_dpp(0, __float_as_int(v), CTRL, 0xF, 0xF, true));
}

#define FMA4S(acc, s, v) do { \
  acc.x = fmaf((s), (v).x, acc.x); \
  acc.y = fmaf((s), (v).y, acc.y); \
  acc.z = fmaf((s), (v).z, acc.z); \
  acc.w = fmaf((s), (v).w, acc.w); } while (0)

#define ACC4(hv, wv, a) do { \
  a = fmaf((hv).x, (wv).x, a); a = fmaf((hv).y, (wv).y, a); \
  a = fmaf((hv).z, (wv).z, a); a = fmaf((hv).w, (wv).w, a); } while (0)

// ---------------------------------------------------------------------------
// K1 v7: gate-per-lane, zero-reduction layout.
// 512 threads (8 waves): lane owns (h = tid>>2, gate = tid&3) and computes the
// FULL 128-long recurrent dot product with the weight row in registers
// (32 x float4 = 128 VGPR).  h is read from LDS as wave-wide BROADCAST
// ds_read_b128 (all lanes same address -> conflict-free).  Gate combine
// (i,f,g,o -> c,h) is 4 quad_perm DPP broadcasts; c is kept redundantly in
// all 4 quad lanes (identical values by construction).
// vs v6: no 3-stage DPP reduce tree, no exec-masked serial activation tail,
// 8 waves instead of 16 at the per-step barrier (half the skew), per-SIMD
// issue/step ~700 cy vs ~1100.  Step loop still has ZERO vm ops (hist in
// LDS, bulk-copied per 64 steps).
// ---------------------------------------------------------------------------
__global__ __launch_bounds__(512, 2) void lstm_kernel(
    const float* __restrict__ x,
    const float* __restrict__ eWih, const float* __restrict__ eWhh, const float* __restrict__ eb,
    const float* __restrict__ dWih, const float* __restrict__ dWhh, const float* __restrict__ db,
    float* __restrict__ encH, float* __restrict__ decH)
{
  const int b   = blockIdx.x;
  const int tid = threadIdx.x;
  const int g   = tid & 3;    // gate: 0=i 1=f 2=g 3=o
  const int i   = tid >> 2;   // h index 0..127

  __shared__ __align__(16) float xs[TT * FIN];     // 6 KB
  __shared__ __align__(16) float hbuf[2][HH];      // 1 KB, double-buffered h
  __shared__ __align__(16) float hist[64 * HH];    // 32 KB: 64-step h history

  if (tid < (TT * FIN / 4))
    ((float4*)xs)[tid] = ((const float4*)(x + (size_t)b * TT * FIN))[tid];
  if (tid < 256) ((float*)hbuf)[tid] = 0.0f;
  float c = 0.0f;  // redundant across the 4 quad lanes

  // activation select, branch-free: gates 0,1,3 sigmoid; gate 2 tanh.
  // sigm(a) = rcp(1+exp2(-log2e*a));  tanh(a) = 1 - 2*rcp(1+exp2(2log2e*a))
  const bool isg = (g == 2);
  const float mk = isg ? TWO_LOG2E : -LOG2E;

  int ts = 0;
  #pragma unroll 1
  for (int phase = 0; phase < 2; ++phase) {
    const float* Wih  = phase ? dWih : eWih;
    const float* Whh  = phase ? dWhh : eWhh;
    const float* bias = phase ? db : eb;
    float* Hout       = phase ? decH : encH;

    // full recurrent weight row in registers: 128 floats
    const int row = g * HH + i;
    float4 wr[32];
    #pragma unroll
    for (int j = 0; j < 32; ++j)
      wr[j] = *(const float4*)(Whh + (size_t)row * HH + 4 * j);

    // input weight row: 12 floats
    float4 wx0 = *(const float4*)(Wih + row * FIN + 0);
    float4 wx1 = *(const float4*)(Wih + row * FIN + 4);
    float4 wx2 = *(const float4*)(Wih + row * FIN + 8);
    const float bb_ = bias[row];

    #pragma unroll 1
    for (int half = 0; half < 2; ++half) {
      #pragma unroll 1
      for (int tt = 0; tt < 64; ++tt, ++ts) {
        const int t = half * 64 + tt;
        __syncthreads();  // h(t) ready in hbuf[ts&1]; hist copy reads done
        const float* hb = hbuf[ts & 1];

        float a0 = 0.f, a1 = 0.f, a2 = 0.f, a3 = 0.f;
        #pragma unroll
        for (int j = 0; j < 8; ++j) {
          float4 h0 = *(const float4*)(hb + 16 * j + 0);
          float4 h1 = *(const float4*)(hb + 16 * j + 4);
          float4 h2 = *(const float4*)(hb + 16 * j + 8);
          float4 h3 = *(const float4*)(hb + 16 * j + 12);
          ACC4(h0, wr[4 * j + 0], a0);
          ACC4(h1, wr[4 * j + 1], a1);
          ACC4(h2, wr[4 * j + 2], a2);
          ACC4(h3, wr[4 * j + 3], a3);
        }
        // x contribution (broadcast reads)
        const float* xt = xs + t * FIN;
        float4 xv0 = *(const float4*)(xt + 0);
        float4 xv1 = *(const float4*)(xt + 4);
        float4 xv2 = *(const float4*)(xt + 8);
        ACC4(xv0, wx0, a0);
        ACC4(xv1, wx1, a1);
        ACC4(xv2, wx2, a2);

        float a = ((a0 + a1) + (a2 + a3)) + bb_;

        // per-lane activation (one transcendental chain per lane)
        float r = frcp(1.0f + fexp2(mk * a));
        float z = isg ? fmaf(-2.0f, r, 1.0f) : r;

        // gather the quad's four gate values (pure VALU, no DS traffic)
        float zi = quad_bcast<0x00>(z);
        float zf = quad_bcast<0x55>(z);
        float zg = quad_bcast<0xAA>(z);
        float zo = quad_bcast<0xFF>(z);

        c = fmaf(zf, c, zi * zg);          // identical in all 4 quad lanes
        float hn = zo * tanh_f(c);
        if (g == 0) {
          hbuf[(ts + 1) & 1][i] = hn;      // 16 lanes/wave, 16 banks: clean
          hist[tt * HH + i] = hn;          // LDS only -- no vm op in step loop
        }
      }
      // bulk-copy this half's history to global (64*128 floats = 2048 f4)
      __syncthreads();  // hist writes visible
      {
        float4* dst = (float4*)(Hout + ((size_t)b * TT + half * 64) * HH);
        const float4* src = (const float4*)hist;
        dst[tid]        = src[tid];
        dst[tid + 512]  = src[tid + 512];
        dst[tid + 1024] = src[tid + 1024];
        dst[tid + 1536] = src[tid + 1536];
      }
      // next half's top-of-loop __syncthreads orders hist reuse; its vmcnt
      // drain absorbs the copy stores once per 64 steps.
    }
  }
}

// ---------------------------------------------------------------------------
// K2: A[b,s,h] = decH[b,s,:]·W1[h,:] + attn_b[h]   (m==0)
//     P[b,t,h] = encH[b,t,:]·W2[h,:]               (m==1)
// grid 1024 = (8 row-tiles x 64 b x 2 m), 256 threads, k-halved LDS W^T.
// ---------------------------------------------------------------------------
__global__ __launch_bounds__(256, 2) void proj_kernel(
    const float* __restrict__ encH, const float* __restrict__ decH,
    const float* __restrict__ attnW, const float* __restrict__ attnb,
    float* __restrict__ Abuf, float* __restrict__ Pbuf)
{
  const int m  = blockIdx.x & 1;
  const int b  = (blockIdx.x >> 1) & 63;
  const int r0 = (blockIdx.x >> 7) * 16;
  const int tid = threadIdx.x;

  __shared__ __align__(16) float WT[64 * 128];  // 32 KB: W^T for a k-half
  __shared__ __align__(16) float Xt[16 * 128];  // 8 KB

  const float* X = (m ? encH : decH) + ((size_t)b * TT + r0) * HH;
  const float* W = attnW + (m ? HH : 0);

  ((float4*)Xt)[tid]       = ((const float4*)X)[tid];
  ((float4*)Xt)[256 + tid] = ((const float4*)X)[256 + tid];

  const int hq = tid & 31, rr = tid >> 5;
  const int h0 = 4 * hq;

  float4 acc0, acc1;
  if (m == 0) { acc0 = *(const float4*)(attnb + h0); acc1 = acc0; }
  else        { acc0 = make_float4(0.f, 0.f, 0.f, 0.f); acc1 = acc0; }

  for (int kb = 0; kb < 2; ++kb) {
    __syncthreads();  // protect WT overwrite
    {
      int h = tid >> 1, koff = (tid & 1) * 32;
      #pragma unroll
      for (int j = 0; j < 8; ++j) {
        float4 v = *(const float4*)(W + h * 256 + kb * 64 + koff + 4 * j);
        int kp = koff + 4 * j;
        WT[(kp + 0) * 128 + h] = v.x;
        WT[(kp + 1) * 128 + h] = v.y;
        WT[(kp + 2) * 128 + h] = v.z;
        WT[(kp + 3) * 128 + h] = v.w;
      }
    }
    __syncthreads();
    const float* xr0 = Xt + (2 * rr) * 128 + kb * 64;
    const float* xr1 = xr0 + 128;
    #pragma unroll
    for (int k4 = 0; k4 < 64; k4 += 4) {
      float4 xa = *(const float4*)(xr0 + k4);
      float4 xb = *(const float4*)(xr1 + k4);
      float4 w0 = *(const float4*)&WT[(k4 + 0) * 128 + h0];
      float4 w1 = *(const float4*)&WT[(k4 + 1) * 128 + h0];
      float4 w2 = *(const float4*)&WT[(k4 + 2) * 128 + h0];
      float4 w3 = *(const float4*)&WT[(k4 + 3) * 128 + h0];
      FMA4S(acc0, xa.x, w0); FMA4S(acc0, xa.y, w1);
      FMA4S(acc0, xa.z, w2); FMA4S(acc0, xa.w, w3);
      FMA4S(acc1, xb.x, w0); FMA4S(acc1, xb.y, w1);
      FMA4S(acc1, xb.z, w2); FMA4S(acc1, xb.w, w3);
    }
  }
  float* O = (m ? Pbuf : Abuf) + ((size_t)b * TT + r0) * HH;
  *(float4*)(O + (2 * rr) * 128 + h0)     = acc0;
  *(float4*)(O + (2 * rr + 1) * 128 + h0) = acc1;
}

// ---------------------------------------------------------------------------
// K3: attention + output. Block = (b, 16 decoder steps). 512 threads.
// t halved so LDS stays < 64 KB; P transposed into LDS with XOR-quad swizzle.
// ---------------------------------------------------------------------------
__global__ __launch_bounds__(512, 2) void attn_kernel(
    const float* __restrict__ encH, const float* __restrict__ decH,
    const float* __restrict__ Abuf, const float* __restrict__ Pbuf,
    const float* __restrict__ vw, const float* __restrict__ outW,
    const float* __restrict__ outb, float* __restrict__ out)
{
  const int b  = blockIdx.x >> 3;
  const int s0 = (blockIdx.x & 7) * 16;
  const int tid = threadIdx.x;

  __shared__ __align__(16) float buf[64 * 128];    // 32 KB: P^T-half (swizzled), later encH-half
  __shared__ __align__(16) float a_lds[16 * 128];  // 8 KB: A tile, later ctx
  __shared__ __align__(16) float sc[16 * 128];     // 8 KB: scores -> weights
  __shared__ __align__(16) float dh[16 * 128];     // 8 KB: decH tile
  __shared__ __align__(16) float vl[HH];

  ((float4*)a_lds)[tid] = ((const float4*)(Abuf + ((size_t)b * TT + s0) * HH))[tid];
  ((float4*)dh)[tid]    = ((const float4*)(decH + ((size_t)b * TT + s0) * HH))[tid];
  if (tid < 32) ((float4*)vl)[tid] = ((const float4*)vw)[tid];

  const int u  = tid & 31;
  const int sl = tid >> 5;   // 0..15 decoder-step within tile
  const int uq = u & 15;     // t-quad within half
  const int uh = u >> 4;     // 0/1 h-half

  // ---- energies/scores ----
  for (int half = 0; half < 2; ++half) {
    const int tbase = half * 64;
    __syncthreads();  // prev buf use done (also covers initial staging)
    #pragma unroll
    for (int i = 0; i < 4; ++i) {
      int flat = i * 2048 + tid * 4;
      int tp = flat >> 7;        // 0..63
      int h0 = flat & 127;
      float4 v = *(const float4*)(Pbuf + ((size_t)b * TT + tbase + tp) * HH + h0);
      int tq = tp >> 2, tr = tp & 3;
      buf[(h0 + 0) * 64 + 4 * ((tq ^ ((h0 + 0) >> 2)) & 15) + tr] = v.x;
      buf[(h0 + 1) * 64 + 4 * ((tq ^ ((h0 + 1) >> 2)) & 15) + tr] = v.y;
      buf[(h0 + 2) * 64 + 4 * ((tq ^ ((h0 + 2) >> 2)) & 15) + tr] = v.z;
      buf[(h0 + 3) * 64 + 4 * ((tq ^ ((h0 + 3) >> 2)) & 15) + tr] = v.w;
    }
    __syncthreads();
    float4 acc = make_float4(0.f, 0.f, 0.f, 0.f);
    const float* arow = a_lds + sl * 128;
    #pragma unroll 8
    for (int hh = 0; hh < 64; ++hh) {
      int h = uh * 64 + hh;
      float ah = arow[h];
      float vh = vl[h];
      float4 p4 = *(const float4*)&buf[h * 64 + 4 * ((uq ^ ((h >> 2) & 15)) & 15)];
      acc.x = fmaf(vh, tanh_f(ah + p4.x), acc.x);
      acc.y = fmaf(vh, tanh_f(ah + p4.y), acc.y);
      acc.z = fmaf(vh, tanh_f(ah + p4.z), acc.z);
      acc.w = fmaf(vh, tanh_f(ah + p4.w), acc.w);
    }
    acc.x += __shfl_xor(acc.x, 16, 64);
    acc.y += __shfl_xor(acc.y, 16, 64);
    acc.z += __shfl_xor(acc.z, 16, 64);
    acc.w += __shfl_xor(acc.w, 16, 64);
    if (uh == 0) *(float4*)&sc[sl * 128 + tbase + 4 * uq] = acc;
  }
  __syncthreads();

  // ---- softmax over t (per s row; 32 lanes x f4 = 128) ----
  {
    float4 sv = *(const float4*)&sc[sl * 128 + 4 * u];
    float mx = fmaxf(fmaxf(sv.x, sv.y), fmaxf(sv.z, sv.w));
    #pragma unroll
    for (int msk = 1; msk <= 16; msk <<= 1) mx = fmaxf(mx, __shfl_xor(mx, msk, 64));
    float4 e;
    e.x = fexp2(LOG2E * (sv.x - mx));
    e.y = fexp2(LOG2E * (sv.y - mx));
    e.z = fexp2(LOG2E * (sv.z - mx));
    e.w = fexp2(LOG2E * (sv.w - mx));
    float sm = (e.x + e.y) + (e.z + e.w);
    #pragma unroll
    for (int msk = 1; msk <= 16; msk <<= 1) sm += __shfl_xor(sm, msk, 64);
    float r = frcp(sm);
    e.x *= r; e.y *= r; e.z *= r; e.w *= r;
    *(float4*)&sc[sl * 128 + 4 * u] = e;
  }

  // ---- ctx = w @ encH ----
  float4 ctx = make_float4(0.f, 0.f, 0.f, 0.f);
  const int h0c = 4 * u;
  for (int half = 0; half < 2; ++half) {
    const int tbase = half * 64;
    __syncthreads();  // buf reuse; also orders softmax writes before reads
    #pragma unroll
    for (int i = 0; i < 4; ++i) {
      int flat = i * 2048 + tid * 4;
      int tp = flat >> 7;
      int hh0 = flat & 127;
      *(float4*)&buf[tp * 128 + hh0] =
          *(const float4*)(encH + ((size_t)b * TT + tbase + tp) * HH + hh0);
    }
    __syncthreads();
    const float* wrow = sc + sl * 128 + tbase;
    #pragma unroll 8
    for (int tp = 0; tp < 64; ++tp) {
      float wt = wrow[tp];
      float4 e4 = *(const float4*)&buf[tp * 128 + h0c];
      FMA4S(ctx, wt, e4);
    }
  }
  __syncthreads();
  *(float4*)&a_lds[sl * 128 + h0c] = ctx;  // overlay A tile with ctx
  __syncthreads();

  // ---- out = [decH, ctx] @ outW^T + outb ----
  if (tid < 192) {
    int s = tid / 12, f = tid % 12;
    float acc = outb[f];
    const float4* w4 = (const float4*)(outW + f * 256);
    const float4* d4 = (const float4*)(dh + s * 128);
    const float4* c4 = (const float4*)(a_lds + s * 128);
    #pragma unroll
    for (int k = 0; k < 32; ++k) {
      float4 wv = w4[k], dv = d4[k];
      acc = fmaf(wv.x, dv.x, acc); acc = fmaf(wv.y, dv.y, acc);
      acc = fmaf(wv.z, dv.z, acc); acc = fmaf(wv.w, dv.w, acc);
    }
    #pragma unroll
    for (int k = 0; k < 32; ++k) {
      float4 wv = w4[32 + k], cv = c4[k];
      acc = fmaf(wv.x, cv.x, acc); acc = fmaf(wv.y, cv.y, acc);
      acc = fmaf(wv.z, cv.z, acc); acc = fmaf(wv.w, cv.w, acc);
    }
    out[((size_t)b * TT + s0 + s) * FIN + f] = acc;
  }
}

// ---------------------------------------------------------------------------
extern "C" void kernel_launch(void* const* d_in, const int* in_sizes, int n_in,
                              void* d_out, int out_size, void* d_ws, size_t ws_size,
                              hipStream_t stream)
{
  const float* x     = (const float*)d_in[0];
  const float* eWih  = (const float*)d_in[1];
  const float* eWhh  = (const float*)d_in[2];
  const float* eb    = (const float*)d_in[3];
  const float* dWih  = (const float*)d_in[4];
  const float* dWhh  = (const float*)d_in[5];
  const float* db    = (const float*)d_in[6];
  const float* attnW = (const float*)d_in[7];
  const float* attnb = (const float*)d_in[8];
  const float* vw    = (const float*)d_in[9];
  const float* outW  = (const float*)d_in[10];
  const float* outb  = (const float*)d_in[11];
  float* out = (float*)d_out;

  float* ws   = (float*)d_ws;
  const size_t SEG = (size_t)BB * TT * HH;  // 1,048,576 floats = 4 MB
  float* encH = ws;
  float* decH = ws + SEG;
  float* Abuf = ws + 2 * SEG;
  float* Pbuf = ws + 3 * SEG;

  lstm_kernel<<<64, 512, 0, stream>>>(x, eWih, eWhh, eb, dWih, dWhh, db, encH, decH);
  proj_kernel<<<1024, 256, 0, stream>>>(encH, decH, attnW, attnb, Abuf, Pbuf);
  attn_kernel<<<512, 512, 0, stream>>>(encH, decH, Abuf, Pbuf, vw, outW, outb, out);
}